// Round 9
// baseline (40978.244 us; speedup 1.0000x reference)
//
#include <hip/hip_runtime.h>
#include <math.h>

#define NN 4096
#define KK 8
#define DD 512
#define HH 512
#define NB 256
#define TPB 1024
#define NXCD 8
#define MAXL 1024
#define LISTSZ (NN + 4 * MAXL)    // level-padded list capacity
#define NNHH ((size_t)NN * HH)

typedef float v2f __attribute__((ext_vector_type(2)));

// ws layout (bytes)
#define OFF_CTRL 0                            // barrier lines (zeroed each launch)
#define OFF_HDR  8192                         // int nlev
#define OFF_LCNT (OFF_HDR + 256)              // int levcnt[MAXL]
#define OFF_LOFF (OFF_LCNT + 4 * MAXL)        // int levoff[MAXL] (4-aligned offsets)
#define OFF_LLEN (OFF_LOFF + 4 * MAXL)        // int levlen[MAXL]
#define OFF_LIST (OFF_LLEN + 4 * MAXL)        // int list[LISTSZ] (i|ll<<12|lr<<16)
#define OFF_XIDX (OFF_LIST + 4 * LISTSZ)      // int xidx[2][9][LISTSZ]
#define OFF_H    (OFF_XIDX + 4 * 2 * 9 * LISTSZ)  // float hbuf[2][2][NN][HH]
#define OFF_C    (OFF_H + 4 * 2 * 2 * NN * HH)    // float cbuf[2][NN][HH]
#define WS_ZERO_BYTES 8192

// tanh(x) = 1 - 2/(exp(2x)+1)  — saturates correctly at +/-inf, ~1e-6 abs err
__device__ __forceinline__ float fast_tanh2x(float two_x) {
    return 1.0f - 2.0f * __builtin_amdgcn_rcpf(__expf(two_x) + 1.0f);
}

// ---------------------------------------------------------------------------
// Prologue (single block): DAG levels + per-level lists + per-substep input
// indices. lev[] lives in LDS (the fixpoint is the hot part).
// ---------------------------------------------------------------------------
__global__ void __launch_bounds__(1024)
sched_kernel(const int* __restrict__ lch, const int* __restrict__ rch, char* ws) {
    const int t = threadIdx.x;
    int* hdr    = (int*)(ws + OFF_HDR);
    int* levcnt = (int*)(ws + OFF_LCNT);
    int* levoff = (int*)(ws + OFF_LOFF);
    int* levlen = (int*)(ws + OFF_LLEN);
    int* list   = (int*)(ws + OFF_LIST);
    int* xidx   = (int*)(ws + OFF_XIDX);

    __shared__ int s_lev[NN];
    __shared__ int s_cnt[MAXL], s_len[MAXL], s_off[MAXL], s_cur[MAXL];
    __shared__ int s_un;

    for (int i = t; i < NN; i += 1024) {
        bool has = false;
#pragma unroll
        for (int k = 0; k < KK; ++k)
            if (lch[i * KK + k] >= 0 || rch[i * KK + k] >= 0) has = true;
        s_lev[i] = has ? -1 : 0;
    }
    for (int l = t; l < MAXL; l += 1024) { s_cnt[l] = 0; s_len[l] = 0; s_cur[l] = 0; }
    __syncthreads();

    // fixpoint: lev[i] = 1 + max(lev[children]); converges in depth iterations
    for (;;) {
        if (t == 0) s_un = 0;
        __syncthreads();
        int myUn = 0;
        for (int i = t; i < NN; i += 1024) {
            if (s_lev[i] < 0) {
                int mx = -1; bool ok = true;
#pragma unroll
                for (int k = 0; k < KK; ++k) {
                    int c = lch[i * KK + k];
                    if (c >= 0) { int lv = s_lev[c]; if (lv < 0) ok = false; else if (lv > mx) mx = lv; }
                    c = rch[i * KK + k];
                    if (c >= 0) { int lv = s_lev[c]; if (lv < 0) ok = false; else if (lv > mx) mx = lv; }
                }
                if (ok) s_lev[i] = mx + 1; else ++myUn;
            }
        }
        if (myUn) atomicAdd(&s_un, myUn);
        __syncthreads();
        if (s_un == 0) break;
        __syncthreads();
    }

    // histogram + per-level max chain length
    for (int i = t; i < NN; i += 1024) {
        const int l = min(s_lev[i], MAXL - 1);
        int ll = 1, lr = 1;
#pragma unroll
        for (int k = 0; k < KK; ++k) {
            if (lch[i * KK + k] >= 0) ll = k + 2;
            if (rch[i * KK + k] >= 0) lr = k + 2;
        }
        atomicAdd(&s_cnt[l], 1);
        atomicMax(&s_len[l], ll > lr ? ll : lr);
    }
    __syncthreads();
    if (t == 0) {
        int off = 0, nl = 0;
        for (int l = 0; l < MAXL; ++l) {
            s_off[l] = off;
            if (s_cnt[l] > 0) { off += s_cnt[l]; off = (off + 3) & ~3; nl = l + 1; }
        }
        hdr[0] = nl;
    }
    __syncthreads();
    // scatter: list entries + per-substep input rows
    for (int i = t; i < NN; i += 1024) {
        const int l = min(s_lev[i], MAXL - 1);
        int ll = 1, lr = 1;
#pragma unroll
        for (int k = 0; k < KK; ++k) {
            if (lch[i * KK + k] >= 0) ll = k + 2;
            if (rch[i * KK + k] >= 0) lr = k + 2;
        }
        const int pos = s_off[l] + atomicAdd(&s_cur[l], 1);
        list[pos] = i | (ll << 12) | (lr << 16);
        xidx[(0 * 9 + 0) * LISTSZ + pos] = i;
        xidx[(1 * 9 + 0) * LISTSZ + pos] = i;
#pragma unroll
        for (int q = 1; q < 9; ++q) {
            xidx[(0 * 9 + q) * LISTSZ + pos] = (q < ll) ? lch[i * KK + q - 1] : -1;
            xidx[(1 * 9 + q) * LISTSZ + pos] = (q < lr) ? rch[i * KK + q - 1] : -1;
        }
    }
    for (int l = t; l < MAXL; l += 1024) {
        levcnt[l] = s_cnt[l]; levoff[l] = s_off[l]; levlen[l] = s_len[l];
    }
}

// ---------------------------------------------------------------------------
// RMW-free grid barrier. r8 lesson: agent-scope atomic RMWs all route to the
// coherent point, so N same-line fetch_adds serialize at ~600-900cy each —
// that WAS the ~15us/barrier. Here: each block STORES its arrival to its own
// dword (256 distinct dwords, fire-and-forget, pipelined); block 0's first
// wave polls all 256 flags in parallel (4/lane + __all), then fans out 8
// per-XCD release flags. All flags monotone in `target` (>= compares). Spin
// polls RELAXED (ACQUIRE polls invalidate caches). One release fence on
// entry, one acquire fence on exit per block.
// SAFE ONLY at <=256 blocks, 1 block/CU (r7: 512-block launch deadlocked).
// ---------------------------------------------------------------------------
__device__ __forceinline__ void grid_barrier(int* ctrl, int blk, int xcd, int target) {
    __syncthreads();
    if (blk == 0) {
        const int t = threadIdx.x;
        if (t < 64) {
            if (t == 0) {
                __builtin_amdgcn_fence(__ATOMIC_RELEASE, "agent");
                __hip_atomic_store(ctrl + 0, target, __ATOMIC_RELAXED, __HIP_MEMORY_SCOPE_AGENT);
            }
            for (;;) {
                const int m0 = __hip_atomic_load(ctrl + t * 4 + 0, __ATOMIC_RELAXED, __HIP_MEMORY_SCOPE_AGENT);
                const int m1 = __hip_atomic_load(ctrl + t * 4 + 1, __ATOMIC_RELAXED, __HIP_MEMORY_SCOPE_AGENT);
                const int m2 = __hip_atomic_load(ctrl + t * 4 + 2, __ATOMIC_RELAXED, __HIP_MEMORY_SCOPE_AGENT);
                const int m3 = __hip_atomic_load(ctrl + t * 4 + 3, __ATOMIC_RELAXED, __HIP_MEMORY_SCOPE_AGENT);
                const bool ok = (m0 >= target) & (m1 >= target) & (m2 >= target) & (m3 >= target);
                if (__all(ok)) break;
                __builtin_amdgcn_s_sleep(1);
            }
            if (t < NXCD)
                __hip_atomic_store(ctrl + 512 + t * 16, target, __ATOMIC_RELAXED, __HIP_MEMORY_SCOPE_AGENT);
            if (t == 0)
                __builtin_amdgcn_fence(__ATOMIC_ACQUIRE, "agent");
        }
    } else {
        if (threadIdx.x == 0) {
            __builtin_amdgcn_fence(__ATOMIC_RELEASE, "agent");
            __hip_atomic_store(ctrl + blk, target, __ATOMIC_RELAXED, __HIP_MEMORY_SCOPE_AGENT);
            while (__hip_atomic_load(ctrl + 512 + xcd * 16, __ATOMIC_RELAXED, __HIP_MEMORY_SCOPE_AGENT) < target)
                __builtin_amdgcn_s_sleep(1);
            __builtin_amdgcn_fence(__ATOMIC_ACQUIRE, "agent");
        }
    }
    __syncthreads();
}

// launch_bounds(1024,2): VGPR cap 256 (r3 proved cap=128 collapses the
// allocator -> spill -> 52 GB HBM). Natural VGPR ~108 -> 16 waves/CU at
// runtime. NB=256 = 1 block/CU: the only grid-barrier-safe grid.
__global__ void __launch_bounds__(TPB, 2)
tree_lstm_kernel(const float* __restrict__ x0,
                 const float* __restrict__ Wl_ih, const float* __restrict__ Wl_hh,
                 const float* __restrict__ bl_ih, const float* __restrict__ bl_hh,
                 const float* __restrict__ Wr_ih, const float* __restrict__ Wr_hh,
                 const float* __restrict__ br_ih, const float* __restrict__ br_hh,
                 const float* __restrict__ W_enc, const float* __restrict__ b_enc,
                 float* ctx, char* ws) {
    const int tid  = threadIdx.x;
    const int wave = (blockIdx.x * TPB + tid) >> 6;  // 0..4095
    const int lane = tid & 63;
    const int u    = wave & 511;       // hidden unit owned by this wave
    const int side = (wave >> 9) & 1;  // 0 = left chain, 1 = right chain
    const int p    = wave >> 10;       // 4-way slot split
    const int egrp = wave >> 9;        // enc: 8-way slot split
    const int xcd  = blockIdx.x & (NXCD - 1);

    int*   ctrl   = (int*)(ws + OFF_CTRL);
    int*   hdr    = (int*)(ws + OFF_HDR);
    int*   levcnt = (int*)(ws + OFF_LCNT);
    int*   levoff = (int*)(ws + OFF_LOFF);
    int*   levlen = (int*)(ws + OFF_LLEN);
    int*   list   = (int*)(ws + OFF_LIST);
    int*   xidx   = (int*)(ws + OFF_XIDX);
    float* hbuf   = (float*)(ws + OFF_H);
    float* cbuf   = (float*)(ws + OFF_C);

    const float* Wih = side ? Wr_ih : Wl_ih;
    const float* Whh = side ? Wr_hh : Wl_hh;
    const float* bih = side ? br_ih : bl_ih;
    const float* bhh = side ? br_hh : bl_hh;

    // Wave-resident weights: 4 gate rows; lane l covers cols [8l,8l+8).
    v2f wih2[4][4], whh2[4][4];
#pragma unroll
    for (int g = 0; g < 4; ++g) {
        const size_t row = (size_t)g * HH + u;
        const float4 wa = *(const float4*)(Wih + row * DD + lane * 8);
        const float4 wb = *(const float4*)(Wih + row * DD + lane * 8 + 4);
        wih2[g][0] = (v2f){wa.x, wa.y}; wih2[g][1] = (v2f){wa.z, wa.w};
        wih2[g][2] = (v2f){wb.x, wb.y}; wih2[g][3] = (v2f){wb.z, wb.w};
        const float4 ha = *(const float4*)(Whh + row * HH + lane * 8);
        const float4 hb = *(const float4*)(Whh + row * HH + lane * 8 + 4);
        whh2[g][0] = (v2f){ha.x, ha.y}; whh2[g][1] = (v2f){ha.z, ha.w};
        whh2[g][2] = (v2f){hb.x, hb.y}; whh2[g][3] = (v2f){hb.z, hb.w};
    }
    // per-lane bias for the gate this lane ends up holding (lane&3)
    const float bsumL = bih[(size_t)(lane & 3) * HH + u] + bhh[(size_t)(lane & 3) * HH + u];
    v2f wenc2[8];
#pragma unroll
    for (int j = 0; j < 4; ++j) {
        const float4 t = *(const float4*)(W_enc + (size_t)u * (2 * HH) + lane * 16 + j * 4);
        wenc2[j * 2 + 0] = (v2f){t.x, t.y};
        wenc2[j * 2 + 1] = (v2f){t.z, t.w};
    }
    const float bencv = b_enc[u];

    const int nlev = hdr[0];
    int bnum = 0;
    int prevBase = 0, prevB = 0;

    for (int r = 0; r < nlev; ++r) {
        const int B = levcnt[r], base = levoff[r], L = levlen[r];
        const int limit = base + B;

        for (int q = 0; q < L; ++q) {
            float*       hb_w = hbuf + (size_t)((q & 1) * 2 + side) * NNHH;
            const float* hb_r = hbuf + (size_t)(((q & 1) ^ 1) * 2 + side) * NNHH;
            float*       cb   = cbuf + (size_t)side * NNHH;
            const int*   xq   = xidx + (size_t)(side * 9 + q) * LISTSZ;
            const float* xbase = (q == 0) ? x0 : ctx;

            for (int s0 = base + p * 4; s0 < limit; s0 += 16) {
                const int4 e4 = *(const int4*)(list + s0);
                const int4 c4 = *(const int4*)(xq + s0);
                const int ei[4] = {e4.x, e4.y, e4.z, e4.w};
                const int ci[4] = {c4.x, c4.y, c4.z, c4.w};
                bool act[4];
                v2f  xr2[4][4], hr2[4][4];
                float cp[4];
#pragma unroll
                for (int k = 0; k < 4; ++k)
                    act[k] = (s0 + k < limit) && (ci[k] >= 0);
                // gather: all loads in flight before compute
#pragma unroll
                for (int k = 0; k < 4; ++k) {
                    if (!act[k]) continue;
                    const float* xv = xbase + (size_t)ci[k] * DD + lane * 8;
                    const float4 xa = *(const float4*)xv;
                    const float4 xb = *(const float4*)(xv + 4);
                    xr2[k][0] = (v2f){xa.x, xa.y}; xr2[k][1] = (v2f){xa.z, xa.w};
                    xr2[k][2] = (v2f){xb.x, xb.y}; xr2[k][3] = (v2f){xb.z, xb.w};
                    if (q > 0) {
                        const int i = ei[k] & 0xFFF;
                        const float* hv = hb_r + (size_t)i * HH + lane * 8;
                        const float4 hA = *(const float4*)hv;
                        const float4 hB = *(const float4*)(hv + 4);
                        hr2[k][0] = (v2f){hA.x, hA.y}; hr2[k][1] = (v2f){hA.z, hA.w};
                        hr2[k][2] = (v2f){hB.x, hB.y}; hr2[k][3] = (v2f){hB.z, hB.w};
                        cp[k] = cb[(size_t)i * HH + u];
                    } else cp[k] = 0.f;
                }
                // compute: 4 independent packed-FMA + reduce + epilogue chains
#pragma unroll
                for (int k = 0; k < 4; ++k) {
                    if (!act[k]) continue;
                    const int i = ei[k] & 0xFFF;
                    v2f A0 = {0.f, 0.f}, A1 = {0.f, 0.f}, A2 = {0.f, 0.f}, A3 = {0.f, 0.f};
#pragma unroll
                    for (int j = 0; j < 4; ++j) {
                        A0 += wih2[0][j] * xr2[k][j];
                        A1 += wih2[1][j] * xr2[k][j];
                        A2 += wih2[2][j] * xr2[k][j];
                        A3 += wih2[3][j] * xr2[k][j];
                    }
                    if (q > 0) {
#pragma unroll
                        for (int j = 0; j < 4; ++j) {
                            A0 += whh2[0][j] * hr2[k][j];
                            A1 += whh2[1][j] * hr2[k][j];
                            A2 += whh2[2][j] * hr2[k][j];
                            A3 += whh2[3][j] * hr2[k][j];
                        }
                    }
                    float a0 = A0[0] + A0[1], a1 = A1[0] + A1[1];
                    float a2 = A2[0] + A2[1], a3 = A3[0] + A3[1];
                    // merge butterfly: lane l ends holding gate (l&3)'s sum
                    float v01, v23, v;
                    {
                        const bool hi = lane & 1;
                        float keep = hi ? a1 : a0, send = hi ? a0 : a1;
                        v01 = keep + __shfl_xor(send, 1, 64);
                        keep = hi ? a3 : a2; send = hi ? a2 : a3;
                        v23 = keep + __shfl_xor(send, 1, 64);
                    }
                    {
                        const bool hi = lane & 2;
                        const float keep = hi ? v23 : v01, send = hi ? v01 : v23;
                        v = keep + __shfl_xor(send, 2, 64);
                    }
                    v += __shfl_xor(v, 4, 64);
                    v += __shfl_xor(v, 8, 64);
                    v += __shfl_xor(v, 16, 64);
                    v += __shfl_xor(v, 32, 64);
                    // wave-parallel nonlinearities: sigm(x)=(tanh(x/2)+1)/2
                    const float gate = v + bsumL;
                    const bool  isG  = (lane & 3) == 2;
                    const float th   = fast_tanh2x(isG ? (gate + gate) : gate);
                    const float tl   = isG ? th : 0.5f * (th + 1.0f);
                    const float ti = __shfl(tl, 0, 64);
                    const float tf = __shfl(tl, 1, 64);
                    const float tg = __shfl(tl, 2, 64);
                    const float to = __shfl(tl, 3, 64);
                    const float cn = tf * cp[k] + ti * tg;
                    const float hn = to * fast_tanh2x(cn + cn);
                    if (lane == 0) {
                        cb[(size_t)i * HH + u]   = cn;
                        hb_w[(size_t)i * HH + u] = hn;
                    }
                }
            }
            if (q == 0 && prevB > 0) {
                // enc for the PREVIOUS round, fused before this barrier
                // (disjoint rows: reads prev nodes' hbuf, writes prev ctx)
                const int lhalf = lane >> 5;
                const int col   = (lane * 16) & 511;
                const int elim  = prevBase + prevB;
                for (int slot = prevBase + egrp; slot < elim; slot += 8) {
                    const int e   = list[slot];
                    const int i   = e & 0xFFF;
                    const int len = (e >> (12 + 4 * lhalf)) & 0xF;
                    const float* hv = hbuf + (size_t)(((len - 1) & 1) * 2 + lhalf) * NNHH
                                    + (size_t)i * HH + col;
                    v2f acc2 = {0.f, 0.f};
#pragma unroll
                    for (int j = 0; j < 4; ++j) {
                        const float4 t = *(const float4*)(hv + j * 4);
                        acc2 += wenc2[j * 2 + 0] * (v2f){t.x, t.y};
                        acc2 += wenc2[j * 2 + 1] * (v2f){t.z, t.w};
                    }
                    float acc = acc2[0] + acc2[1];
#pragma unroll
                    for (int m = 1; m < 64; m <<= 1) acc += __shfl_xor(acc, m, 64);
                    if (lane == 0)
                        ctx[(size_t)i * DD + u] = fast_tanh2x(2.0f * (acc + bencv));
                }
            }
            grid_barrier(ctrl, blockIdx.x, xcd, ++bnum);
        }
        prevBase = base; prevB = B;
    }
    // final round's enc (h published by the last substep barrier)
    {
        const int lhalf = lane >> 5;
        const int col   = (lane * 16) & 511;
        const int elim  = prevBase + prevB;
        for (int slot = prevBase + egrp; slot < elim; slot += 8) {
            const int e   = list[slot];
            const int i   = e & 0xFFF;
            const int len = (e >> (12 + 4 * lhalf)) & 0xF;
            const float* hv = hbuf + (size_t)(((len - 1) & 1) * 2 + lhalf) * NNHH
                            + (size_t)i * HH + col;
            v2f acc2 = {0.f, 0.f};
#pragma unroll
            for (int j = 0; j < 4; ++j) {
                const float4 t = *(const float4*)(hv + j * 4);
                acc2 += wenc2[j * 2 + 0] * (v2f){t.x, t.y};
                acc2 += wenc2[j * 2 + 1] * (v2f){t.z, t.w};
            }
            float acc = acc2[0] + acc2[1];
#pragma unroll
            for (int m = 1; m < 64; m <<= 1) acc += __shfl_xor(acc, m, 64);
            if (lane == 0)
                ctx[(size_t)i * DD + u] = fast_tanh2x(2.0f * (acc + bencv));
        }
    }
}

extern "C" void kernel_launch(void* const* d_in, const int* in_sizes, int n_in,
                              void* d_out, int out_size, void* d_ws, size_t ws_size,
                              hipStream_t stream) {
    hipMemsetAsync(d_ws, 0, WS_ZERO_BYTES, stream);
    sched_kernel<<<dim3(1), dim3(1024), 0, stream>>>(
        (const int*)d_in[11], (const int*)d_in[12], (char*)d_ws);
    tree_lstm_kernel<<<dim3(NB), dim3(TPB), 0, stream>>>(
        (const float*)d_in[0],
        (const float*)d_in[1], (const float*)d_in[2],
        (const float*)d_in[3], (const float*)d_in[4],
        (const float*)d_in[5], (const float*)d_in[6],
        (const float*)d_in[7], (const float*)d_in[8],
        (const float*)d_in[9], (const float*)d_in[10],
        (float*)d_out, (char*)d_ws);
}

// Round 10
// 18395.027 us; speedup vs baseline: 2.2277x; 2.2277x over previous
//
#include <hip/hip_runtime.h>
#include <math.h>

#define NN 4096
#define KK 8
#define DD 512
#define HH 512
#define NB 256
#define TPB 512
#define NXCD 8
#define MAXL 1024
#define LISTSZ (NN + 4 * MAXL)    // level-padded list capacity
#define NNHH ((size_t)NN * HH)

typedef float v2f __attribute__((ext_vector_type(2)));

// ws layout (bytes)
#define OFF_CTRL 0                            // barrier lines (zeroed each launch)
#define OFF_HDR  8192                         // int nlev
#define OFF_LCNT (OFF_HDR + 256)              // int levcnt[MAXL]
#define OFF_LOFF (OFF_LCNT + 4 * MAXL)        // int levoff[MAXL] (4-aligned offsets)
#define OFF_LLEN (OFF_LOFF + 4 * MAXL)        // int levlen[MAXL]
#define OFF_LIST (OFF_LLEN + 4 * MAXL)        // int list[LISTSZ] (i|ll<<12|lr<<16)
#define OFF_XIDX (OFF_LIST + 4 * LISTSZ)      // int xidx[2][9][LISTSZ]
#define OFF_H    (OFF_XIDX + 4 * 2 * 9 * LISTSZ)  // float hbuf[2][2][NN][HH]
#define OFF_C    (OFF_H + 4 * 2 * 2 * NN * HH)    // float cbuf[2][NN][HH]
#define WS_ZERO_BYTES 8192

// tanh(x) = 1 - 2/(exp(2x)+1)  — saturates correctly at +/-inf, ~1e-6 abs err
__device__ __forceinline__ float fast_tanh2x(float two_x) {
    return 1.0f - 2.0f * __builtin_amdgcn_rcpf(__expf(two_x) + 1.0f);
}

// ---------------------------------------------------------------------------
// Prologue (single block): DAG levels + per-level lists + per-substep input
// indices. lev[] lives in LDS (the fixpoint is the hot part).
// ---------------------------------------------------------------------------
__global__ void __launch_bounds__(1024)
sched_kernel(const int* __restrict__ lch, const int* __restrict__ rch, char* ws) {
    const int t = threadIdx.x;
    int* hdr    = (int*)(ws + OFF_HDR);
    int* levcnt = (int*)(ws + OFF_LCNT);
    int* levoff = (int*)(ws + OFF_LOFF);
    int* levlen = (int*)(ws + OFF_LLEN);
    int* list   = (int*)(ws + OFF_LIST);
    int* xidx   = (int*)(ws + OFF_XIDX);

    __shared__ int s_lev[NN];
    __shared__ int s_cnt[MAXL], s_len[MAXL], s_off[MAXL], s_cur[MAXL];
    __shared__ int s_un;

    for (int i = t; i < NN; i += 1024) {
        bool has = false;
#pragma unroll
        for (int k = 0; k < KK; ++k)
            if (lch[i * KK + k] >= 0 || rch[i * KK + k] >= 0) has = true;
        s_lev[i] = has ? -1 : 0;
    }
    for (int l = t; l < MAXL; l += 1024) { s_cnt[l] = 0; s_len[l] = 0; s_cur[l] = 0; }
    __syncthreads();

    // fixpoint: lev[i] = 1 + max(lev[children]); converges in depth iterations
    for (;;) {
        if (t == 0) s_un = 0;
        __syncthreads();
        int myUn = 0;
        for (int i = t; i < NN; i += 1024) {
            if (s_lev[i] < 0) {
                int mx = -1; bool ok = true;
#pragma unroll
                for (int k = 0; k < KK; ++k) {
                    int c = lch[i * KK + k];
                    if (c >= 0) { int lv = s_lev[c]; if (lv < 0) ok = false; else if (lv > mx) mx = lv; }
                    c = rch[i * KK + k];
                    if (c >= 0) { int lv = s_lev[c]; if (lv < 0) ok = false; else if (lv > mx) mx = lv; }
                }
                if (ok) s_lev[i] = mx + 1; else ++myUn;
            }
        }
        if (myUn) atomicAdd(&s_un, myUn);
        __syncthreads();
        if (s_un == 0) break;
        __syncthreads();
    }

    // histogram + per-level max chain length
    for (int i = t; i < NN; i += 1024) {
        const int l = min(s_lev[i], MAXL - 1);
        int ll = 1, lr = 1;
#pragma unroll
        for (int k = 0; k < KK; ++k) {
            if (lch[i * KK + k] >= 0) ll = k + 2;
            if (rch[i * KK + k] >= 0) lr = k + 2;
        }
        atomicAdd(&s_cnt[l], 1);
        atomicMax(&s_len[l], ll > lr ? ll : lr);
    }
    __syncthreads();
    if (t == 0) {
        int off = 0, nl = 0;
        for (int l = 0; l < MAXL; ++l) {
            s_off[l] = off;
            if (s_cnt[l] > 0) { off += s_cnt[l]; off = (off + 3) & ~3; nl = l + 1; }
        }
        hdr[0] = nl;
    }
    __syncthreads();
    // scatter: list entries + per-substep input rows
    for (int i = t; i < NN; i += 1024) {
        const int l = min(s_lev[i], MAXL - 1);
        int ll = 1, lr = 1;
#pragma unroll
        for (int k = 0; k < KK; ++k) {
            if (lch[i * KK + k] >= 0) ll = k + 2;
            if (rch[i * KK + k] >= 0) lr = k + 2;
        }
        const int pos = s_off[l] + atomicAdd(&s_cur[l], 1);
        list[pos] = i | (ll << 12) | (lr << 16);
        xidx[(0 * 9 + 0) * LISTSZ + pos] = i;
        xidx[(1 * 9 + 0) * LISTSZ + pos] = i;
#pragma unroll
        for (int q = 1; q < 9; ++q) {
            xidx[(0 * 9 + q) * LISTSZ + pos] = (q < ll) ? lch[i * KK + q - 1] : -1;
            xidx[(1 * 9 + q) * LISTSZ + pos] = (q < lr) ? rch[i * KK + q - 1] : -1;
        }
    }
    for (int l = t; l < MAXL; l += 1024) {
        levcnt[l] = s_cnt[l]; levoff[l] = s_off[l]; levlen[l] = s_len[l];
    }
}

// ---------------------------------------------------------------------------
// RMW-free grid barrier (r8 lesson: agent-scope atomic RMWs serialize at the
// coherent point, ~25us/barrier at 256 arrivals). Each block STORES its
// arrival to its own dword (256 independent dwords — fire-and-forget,
// pipelined); block 0's first wave polls all 256 flags in parallel (4/lane +
// __all), then fans out 8 per-XCD release flags. All flags monotone in
// `target` (>= compares; leaders may run ahead safely). Spin polls RELAXED
// (ACQUIRE polls invalidate caches every iteration — chip-wide poison). One
// release fence on entry, one acquire fence on exit per block.
// SAFE ONLY at <=256 blocks, 1 block/CU (r7: 512-block launch deadlocked).
// ---------------------------------------------------------------------------
__device__ __forceinline__ void grid_barrier(int* ctrl, int blk, int xcd, int target) {
    __syncthreads();
    if (blk == 0) {
        const int t = threadIdx.x;
        if (t < 64) {
            if (t == 0) {
                __builtin_amdgcn_fence(__ATOMIC_RELEASE, "agent");
                __hip_atomic_store(ctrl + 0, target, __ATOMIC_RELAXED, __HIP_MEMORY_SCOPE_AGENT);
            }
            for (;;) {
                const int m0 = __hip_atomic_load(ctrl + t * 4 + 0, __ATOMIC_RELAXED, __HIP_MEMORY_SCOPE_AGENT);
                const int m1 = __hip_atomic_load(ctrl + t * 4 + 1, __ATOMIC_RELAXED, __HIP_MEMORY_SCOPE_AGENT);
                const int m2 = __hip_atomic_load(ctrl + t * 4 + 2, __ATOMIC_RELAXED, __HIP_MEMORY_SCOPE_AGENT);
                const int m3 = __hip_atomic_load(ctrl + t * 4 + 3, __ATOMIC_RELAXED, __HIP_MEMORY_SCOPE_AGENT);
                const bool ok = (m0 >= target) & (m1 >= target) & (m2 >= target) & (m3 >= target);
                if (__all(ok)) break;
                __builtin_amdgcn_s_sleep(1);
            }
            if (t < NXCD)
                __hip_atomic_store(ctrl + 512 + t * 16, target, __ATOMIC_RELAXED, __HIP_MEMORY_SCOPE_AGENT);
            if (t == 0)
                __builtin_amdgcn_fence(__ATOMIC_ACQUIRE, "agent");
        }
    } else {
        if (threadIdx.x == 0) {
            __builtin_amdgcn_fence(__ATOMIC_RELEASE, "agent");
            __hip_atomic_store(ctrl + blk, target, __ATOMIC_RELAXED, __HIP_MEMORY_SCOPE_AGENT);
            while (__hip_atomic_load(ctrl + 512 + xcd * 16, __ATOMIC_RELAXED, __HIP_MEMORY_SCOPE_AGENT) < target)
                __builtin_amdgcn_s_sleep(1);
            __builtin_amdgcn_fence(__ATOMIC_ACQUIRE, "agent");
        }
    }
    __syncthreads();
}

// REGISTER ENVELOPE LAW (r3, r9): TPB=512 + __launch_bounds__(512,2) is the
// ONLY proven config keeping the weight hoist in registers (VGPR 108-116).
// (1024,2) -> 64-VGPR cap -> spill -> 47 GB scratch traffic (r9).
// (512,4)  -> 128-cap -> same collapse (r3). DO NOT TOUCH.
__global__ void __launch_bounds__(TPB, 2)
tree_lstm_kernel(const float* __restrict__ x0,
                 const float* __restrict__ Wl_ih, const float* __restrict__ Wl_hh,
                 const float* __restrict__ bl_ih, const float* __restrict__ bl_hh,
                 const float* __restrict__ Wr_ih, const float* __restrict__ Wr_hh,
                 const float* __restrict__ br_ih, const float* __restrict__ br_hh,
                 const float* __restrict__ W_enc, const float* __restrict__ b_enc,
                 float* ctx, char* ws) {
    const int tid  = threadIdx.x;
    const int wave = (blockIdx.x * TPB + tid) >> 6;  // 0..2047
    const int lane = tid & 63;
    const int u    = wave & 511;       // hidden unit owned by this wave
    const int side = (wave >> 9) & 1;  // 0 = left chain, 1 = right chain
    const int p    = wave >> 10;       // 2-way slot split
    const int egrp = wave >> 9;        // enc: 4-way slot split
    const int xcd  = blockIdx.x & (NXCD - 1);

    int*   ctrl   = (int*)(ws + OFF_CTRL);
    int*   hdr    = (int*)(ws + OFF_HDR);
    int*   levcnt = (int*)(ws + OFF_LCNT);
    int*   levoff = (int*)(ws + OFF_LOFF);
    int*   levlen = (int*)(ws + OFF_LLEN);
    int*   list   = (int*)(ws + OFF_LIST);
    int*   xidx   = (int*)(ws + OFF_XIDX);
    float* hbuf   = (float*)(ws + OFF_H);
    float* cbuf   = (float*)(ws + OFF_C);

    const float* Wih = side ? Wr_ih : Wl_ih;
    const float* Whh = side ? Wr_hh : Wl_hh;
    const float* bih = side ? br_ih : bl_ih;
    const float* bhh = side ? br_hh : bl_hh;

    // Wave-resident weights: 4 gate rows; lane l covers cols [8l,8l+8).
    v2f wih2[4][4], whh2[4][4];
#pragma unroll
    for (int g = 0; g < 4; ++g) {
        const size_t row = (size_t)g * HH + u;
        const float4 wa = *(const float4*)(Wih + row * DD + lane * 8);
        const float4 wb = *(const float4*)(Wih + row * DD + lane * 8 + 4);
        wih2[g][0] = (v2f){wa.x, wa.y}; wih2[g][1] = (v2f){wa.z, wa.w};
        wih2[g][2] = (v2f){wb.x, wb.y}; wih2[g][3] = (v2f){wb.z, wb.w};
        const float4 ha = *(const float4*)(Whh + row * HH + lane * 8);
        const float4 hb = *(const float4*)(Whh + row * HH + lane * 8 + 4);
        whh2[g][0] = (v2f){ha.x, ha.y}; whh2[g][1] = (v2f){ha.z, ha.w};
        whh2[g][2] = (v2f){hb.x, hb.y}; whh2[g][3] = (v2f){hb.z, hb.w};
    }
    // per-lane bias for the gate this lane ends up holding (lane&3)
    const float bsumL = bih[(size_t)(lane & 3) * HH + u] + bhh[(size_t)(lane & 3) * HH + u];
    v2f wenc2[8];
#pragma unroll
    for (int j = 0; j < 4; ++j) {
        const float4 t = *(const float4*)(W_enc + (size_t)u * (2 * HH) + lane * 16 + j * 4);
        wenc2[j * 2 + 0] = (v2f){t.x, t.y};
        wenc2[j * 2 + 1] = (v2f){t.z, t.w};
    }
    const float bencv = b_enc[u];

    const int nlev = hdr[0];
    int bnum = 0;
    int prevBase = 0, prevB = 0;

    for (int r = 0; r < nlev; ++r) {
        const int B = levcnt[r], base = levoff[r], L = levlen[r];
        const int limit = base + B;

        for (int q = 0; q < L; ++q) {
            float*       hb_w = hbuf + (size_t)((q & 1) * 2 + side) * NNHH;
            const float* hb_r = hbuf + (size_t)(((q & 1) ^ 1) * 2 + side) * NNHH;
            float*       cb   = cbuf + (size_t)side * NNHH;
            const int*   xq   = xidx + (size_t)(side * 9 + q) * LISTSZ;
            const float* xbase = (q == 0) ? x0 : ctx;

            for (int s0 = base + p * 4; s0 < limit; s0 += 8) {
                const int4 e4 = *(const int4*)(list + s0);
                const int4 c4 = *(const int4*)(xq + s0);
                const int ei[4] = {e4.x, e4.y, e4.z, e4.w};
                const int ci[4] = {c4.x, c4.y, c4.z, c4.w};
                bool act[4];
                v2f  xr2[4][4], hr2[4][4];
                float cp[4];
#pragma unroll
                for (int k = 0; k < 4; ++k)
                    act[k] = (s0 + k < limit) && (ci[k] >= 0);
                // gather: all loads in flight before compute
#pragma unroll
                for (int k = 0; k < 4; ++k) {
                    if (!act[k]) continue;
                    const float* xv = xbase + (size_t)ci[k] * DD + lane * 8;
                    const float4 xa = *(const float4*)xv;
                    const float4 xb = *(const float4*)(xv + 4);
                    xr2[k][0] = (v2f){xa.x, xa.y}; xr2[k][1] = (v2f){xa.z, xa.w};
                    xr2[k][2] = (v2f){xb.x, xb.y}; xr2[k][3] = (v2f){xb.z, xb.w};
                    if (q > 0) {
                        const int i = ei[k] & 0xFFF;
                        const float* hv = hb_r + (size_t)i * HH + lane * 8;
                        const float4 hA = *(const float4*)hv;
                        const float4 hB = *(const float4*)(hv + 4);
                        hr2[k][0] = (v2f){hA.x, hA.y}; hr2[k][1] = (v2f){hA.z, hA.w};
                        hr2[k][2] = (v2f){hB.x, hB.y}; hr2[k][3] = (v2f){hB.z, hB.w};
                        cp[k] = cb[(size_t)i * HH + u];
                    } else cp[k] = 0.f;
                }
                // compute: 4 independent packed-FMA + reduce + epilogue chains
#pragma unroll
                for (int k = 0; k < 4; ++k) {
                    if (!act[k]) continue;
                    const int i = ei[k] & 0xFFF;
                    v2f A0 = {0.f, 0.f}, A1 = {0.f, 0.f}, A2 = {0.f, 0.f}, A3 = {0.f, 0.f};
#pragma unroll
                    for (int j = 0; j < 4; ++j) {
                        A0 += wih2[0][j] * xr2[k][j];
                        A1 += wih2[1][j] * xr2[k][j];
                        A2 += wih2[2][j] * xr2[k][j];
                        A3 += wih2[3][j] * xr2[k][j];
                    }
                    if (q > 0) {
#pragma unroll
                        for (int j = 0; j < 4; ++j) {
                            A0 += whh2[0][j] * hr2[k][j];
                            A1 += whh2[1][j] * hr2[k][j];
                            A2 += whh2[2][j] * hr2[k][j];
                            A3 += whh2[3][j] * hr2[k][j];
                        }
                    }
                    float a0 = A0[0] + A0[1], a1 = A1[0] + A1[1];
                    float a2 = A2[0] + A2[1], a3 = A3[0] + A3[1];
                    // merge butterfly: lane l ends holding gate (l&3)'s sum
                    float v01, v23, v;
                    {
                        const bool hi = lane & 1;
                        float keep = hi ? a1 : a0, send = hi ? a0 : a1;
                        v01 = keep + __shfl_xor(send, 1, 64);
                        keep = hi ? a3 : a2; send = hi ? a2 : a3;
                        v23 = keep + __shfl_xor(send, 1, 64);
                    }
                    {
                        const bool hi = lane & 2;
                        const float keep = hi ? v23 : v01, send = hi ? v01 : v23;
                        v = keep + __shfl_xor(send, 2, 64);
                    }
                    v += __shfl_xor(v, 4, 64);
                    v += __shfl_xor(v, 8, 64);
                    v += __shfl_xor(v, 16, 64);
                    v += __shfl_xor(v, 32, 64);
                    // wave-parallel nonlinearities: sigm(x)=(tanh(x/2)+1)/2
                    const float gate = v + bsumL;
                    const bool  isG  = (lane & 3) == 2;
                    const float th   = fast_tanh2x(isG ? (gate + gate) : gate);
                    const float tl   = isG ? th : 0.5f * (th + 1.0f);
                    const float ti = __shfl(tl, 0, 64);
                    const float tf = __shfl(tl, 1, 64);
                    const float tg = __shfl(tl, 2, 64);
                    const float to = __shfl(tl, 3, 64);
                    const float cn = tf * cp[k] + ti * tg;
                    const float hn = to * fast_tanh2x(cn + cn);
                    if (lane == 0) {
                        cb[(size_t)i * HH + u]   = cn;
                        hb_w[(size_t)i * HH + u] = hn;
                    }
                }
            }
            if (q == 0 && prevB > 0) {
                // enc for the PREVIOUS round, fused before this barrier
                // (disjoint rows: reads prev nodes' hbuf, writes prev ctx)
                const int lhalf = lane >> 5;
                const int col   = (lane * 16) & 511;
                const int elim  = prevBase + prevB;
                for (int slot = prevBase + egrp; slot < elim; slot += 4) {
                    const int e   = list[slot];
                    const int i   = e & 0xFFF;
                    const int len = (e >> (12 + 4 * lhalf)) & 0xF;
                    const float* hv = hbuf + (size_t)(((len - 1) & 1) * 2 + lhalf) * NNHH
                                    + (size_t)i * HH + col;
                    v2f acc2 = {0.f, 0.f};
#pragma unroll
                    for (int j = 0; j < 4; ++j) {
                        const float4 t = *(const float4*)(hv + j * 4);
                        acc2 += wenc2[j * 2 + 0] * (v2f){t.x, t.y};
                        acc2 += wenc2[j * 2 + 1] * (v2f){t.z, t.w};
                    }
                    float acc = acc2[0] + acc2[1];
#pragma unroll
                    for (int m = 1; m < 64; m <<= 1) acc += __shfl_xor(acc, m, 64);
                    if (lane == 0)
                        ctx[(size_t)i * DD + u] = fast_tanh2x(2.0f * (acc + bencv));
                }
            }
            grid_barrier(ctrl, blockIdx.x, xcd, ++bnum);
        }
        prevBase = base; prevB = B;
    }
    // final round's enc (h published by the last substep barrier)
    {
        const int lhalf = lane >> 5;
        const int col   = (lane * 16) & 511;
        const int elim  = prevBase + prevB;
        for (int slot = prevBase + egrp; slot < elim; slot += 4) {
            const int e   = list[slot];
            const int i   = e & 0xFFF;
            const int len = (e >> (12 + 4 * lhalf)) & 0xF;
            const float* hv = hbuf + (size_t)(((len - 1) & 1) * 2 + lhalf) * NNHH
                            + (size_t)i * HH + col;
            v2f acc2 = {0.f, 0.f};
#pragma unroll
            for (int j = 0; j < 4; ++j) {
                const float4 t = *(const float4*)(hv + j * 4);
                acc2 += wenc2[j * 2 + 0] * (v2f){t.x, t.y};
                acc2 += wenc2[j * 2 + 1] * (v2f){t.z, t.w};
            }
            float acc = acc2[0] + acc2[1];
#pragma unroll
            for (int m = 1; m < 64; m <<= 1) acc += __shfl_xor(acc, m, 64);
            if (lane == 0)
                ctx[(size_t)i * DD + u] = fast_tanh2x(2.0f * (acc + bencv));
        }
    }
}

extern "C" void kernel_launch(void* const* d_in, const int* in_sizes, int n_in,
                              void* d_out, int out_size, void* d_ws, size_t ws_size,
                              hipStream_t stream) {
    hipMemsetAsync(d_ws, 0, WS_ZERO_BYTES, stream);
    sched_kernel<<<dim3(1), dim3(1024), 0, stream>>>(
        (const int*)d_in[11], (const int*)d_in[12], (char*)d_ws);
    tree_lstm_kernel<<<dim3(NB), dim3(TPB), 0, stream>>>(
        (const float*)d_in[0],
        (const float*)d_in[1], (const float*)d_in[2],
        (const float*)d_in[3], (const float*)d_in[4],
        (const float*)d_in[5], (const float*)d_in[6],
        (const float*)d_in[7], (const float*)d_in[8],
        (const float*)d_in[9], (const float*)d_in[10],
        (float*)d_out, (char*)d_ws);
}